// Round 3
// baseline (311.046 us; speedup 1.0000x reference)
//
#include <hip/hip_runtime.h>

#define N_NODES 100000
#define N_EDGES 1600000
#define IN_DIM 128
#define HID_DIM 128
#define OUT_DIM 64
#define BKT_SHIFT 7
#define BKT_SIZE 128
#define NBKT ((N_NODES + BKT_SIZE - 1) / BKT_SIZE)  // 782
#define B1 256                                       // hist/scatter blocks
#define HIST_N (NBKT * B1)                           // 200192
#define HIST_N2 (2 * HIST_N)                         // 400384
#define GEMM_BLKS ((N_NODES + 127) / 128)            // 782
#define AGG_BLKS 2048
#define NPW 49  // nodes per wave: ceil(100000 / 2048) per quarter (2048 waves/quarter)

typedef float v2f __attribute__((ext_vector_type(2)));
typedef float v4f __attribute__((ext_vector_type(4)));
typedef short v8s __attribute__((ext_vector_type(8)));

// XCD-affine slot permutation: adjacent hist slots belong to same-XCD blocks.
__device__ __forceinline__ int permb(int b) { return ((b & 7) << 5) | (b >> 3); }

// ---------- helpers ----------
__device__ __forceinline__ unsigned int f2bf(float f) {  // fp32->bf16 RNE
  unsigned int u = __float_as_uint(f);
  return (u + 0x7FFFu + ((u >> 16) & 1u)) >> 16;
}

template <bool HI>
__device__ __forceinline__ v2f cvt8(unsigned int u) {
  return __builtin_amdgcn_cvt_pk_f32_fp8((int)u, HI);  // word-select immediate
}

__device__ __forceinline__ float wdec(unsigned int p) {  // bf16 weight, bits [17,32)
  return __uint_as_float((p >> 17) << 16);
}

__device__ __forceinline__ void load4(const void* ei, int is64, int half, int base,
                                      int* v) {
  if (is64) {
    const long long* e = (const long long*)ei + (size_t)half * N_EDGES + base;
    longlong2 a = *(const longlong2*)e;
    longlong2 b = *(const longlong2*)(e + 2);
    v[0] = (int)a.x; v[1] = (int)a.y; v[2] = (int)b.x; v[3] = (int)b.y;
  } else {
    const int* e = (const int*)ei + (size_t)half * N_EDGES + base;
    int4 a = *(const int4*)e;
    v[0] = a.x; v[1] = a.y; v[2] = a.z; v[3] = a.w;
  }
}

// block-local int64 detection: odd dwords of first 256 int64 entries all zero
__device__ __forceinline__ int detect64_block(const unsigned int* ei, int* sh) {
  if (threadIdx.x == 0) *sh = 0;
  __syncthreads();
  if (ei[1 + 2 * threadIdx.x] != 0u) *sh = 1;
  __syncthreads();
  return (*sh == 0) ? 1 : 0;
}

// ---------- front kernel: blocks [0,782) = raw GEMM; [782,1038) = hist ----------
// G layout is quarter-major: G8[(q*N_NODES + row)*32 + (col&31)], q = col>>5.
__global__ __launch_bounds__(256) void front_kernel(const float* __restrict__ x,
                                                    const float* __restrict__ W,
                                                    const void* ei,
                                                    unsigned int* __restrict__ G,
                                                    int* hist, float* S) {
  __shared__ __align__(16) char smem[2 * 128 * 136 * 2];  // 69632 B
  if (blockIdx.x >= GEMM_BLKS) {
    // ---- hist role ----
    int* hd = (int*)smem;           // NBKT
    int* hs = hd + NBKT;            // NBKT
    int* sh = hs + NBKT;
    const int hb = blockIdx.x - GEMM_BLKS;
    const int pj = permb(hb);       // XCD-affine slot
    if (hb == 0 && threadIdx.x < HID_DIM) S[threadIdx.x] = 0.f;
    const int is64 = detect64_block((const unsigned int*)ei, sh);
    for (int k = threadIdx.x; k < NBKT; k += 256) { hd[k] = 0; hs[k] = 0; }
    __syncthreads();
    for (int g = hb * 256 + threadIdx.x; g < N_EDGES / 4; g += B1 * 256) {
      int r[4], c[4];
      load4(ei, is64, 0, g * 4, r);
      load4(ei, is64, 1, g * 4, c);
#pragma unroll
      for (int k = 0; k < 4; k++) {
        atomicAdd(&hd[c[k] >> BKT_SHIFT], 1);
        atomicAdd(&hs[r[k] >> BKT_SHIFT], 1);
      }
    }
    __syncthreads();
    for (int k = threadIdx.x; k < NBKT; k += 256) {
      hist[k * B1 + pj] = hd[k];
      hist[HIST_N + k * B1 + pj] = hs[k];
    }
    return;
  }
  // ---- gemm role: G_raw(fp8) = x @ W1, bf16 MFMA ----
  typedef unsigned short us_row[136];
  us_row* lx = (us_row*)smem;
  us_row* lwt = (us_row*)(smem + 128 * 136 * 2);
  const int t = threadIdx.x;
  const int row0 = blockIdx.x * 128;

  {  // stage W^T bf16
    const float4* W4 = (const float4*)W;
    for (int it = 0; it < 16; ++it) {
      int idx = t + 256 * it;  // k*32 + c4
      int k = idx >> 5, c4 = (idx & 31) * 4;
      float4 w = W4[idx];
      lwt[c4 + 0][k] = (unsigned short)f2bf(w.x);
      lwt[c4 + 1][k] = (unsigned short)f2bf(w.y);
      lwt[c4 + 2][k] = (unsigned short)f2bf(w.z);
      lwt[c4 + 3][k] = (unsigned short)f2bf(w.w);
    }
  }
  {  // stage x tile bf16
    const float4* x4 = (const float4*)(x + (size_t)row0 * IN_DIM);
    for (int it = 0; it < 16; ++it) {
      int idx = t + 256 * it;  // r*32 + kq4
      int r = idx >> 5, kq = (idx & 31) * 4;
      float4 v = make_float4(0.f, 0.f, 0.f, 0.f);
      if (row0 + r < N_NODES) v = x4[idx];
      unsigned int p0 = (f2bf(v.y) << 16) | f2bf(v.x);
      unsigned int p1 = (f2bf(v.w) << 16) | f2bf(v.z);
      *(uint2*)&lx[r][kq] = make_uint2(p0, p1);
    }
  }
  __syncthreads();

  const int lane = t & 63;
  const int wv = t >> 6;
  const int m0 = wv * 32;
  const int lrow = lane & 15;
  const int lk = (lane >> 4) * 8;

  v4f acc[2][8];
#pragma unroll
  for (int si = 0; si < 2; si++)
#pragma unroll
    for (int n = 0; n < 8; n++) acc[si][n] = (v4f){0.f, 0.f, 0.f, 0.f};

#pragma unroll
  for (int kk = 0; kk < 128; kk += 32) {
    v8s a0 = *(const v8s*)&lx[m0 + lrow][kk + lk];
    v8s a1 = *(const v8s*)&lx[m0 + 16 + lrow][kk + lk];
#pragma unroll
    for (int n = 0; n < 8; n++) {
      v8s b = *(const v8s*)&lwt[n * 16 + lrow][kk + lk];
      acc[0][n] = __builtin_amdgcn_mfma_f32_16x16x32_bf16(a0, b, acc[0][n], 0, 0, 0);
      acc[1][n] = __builtin_amdgcn_mfma_f32_16x16x32_bf16(a1, b, acc[1][n], 0, 0, 0);
    }
  }

  unsigned char* G8 = (unsigned char*)G;
#pragma unroll
  for (int si = 0; si < 2; si++)
#pragma unroll
    for (int n = 0; n < 8; n++) {
      int colg = n * 16 + (lane & 15);
#pragma unroll
      for (int i = 0; i < 4; i++) {
        int r = row0 + m0 + si * 16 + (lane >> 4) * 4 + i;
        if (r < N_NODES) {
          float v = acc[si][n][i];
          int pk = __builtin_amdgcn_cvt_pk_fp8_f32(v, v, 0, false);
          G8[((size_t)(colg >> 5) * N_NODES + r) * 32 + (colg & 31)] =
              (unsigned char)(pk & 0xFF);
        }
      }
    }
}

// ---------- scan1: per-block exclusive partials + block sums ----------
__global__ void scan1_kernel(int* arr, int* bsum, int n) {
  __shared__ int tmp[256];
  int i = blockIdx.x * 256 + threadIdx.x;
  int v = (i < n) ? arr[i] : 0;
  tmp[threadIdx.x] = v;
  __syncthreads();
  for (int off = 1; off < 256; off <<= 1) {
    int t2 = (threadIdx.x >= off) ? tmp[threadIdx.x - off] : 0;
    __syncthreads();
    tmp[threadIdx.x] += t2;
    __syncthreads();
  }
  if (i < n) arr[i] = tmp[threadIdx.x] - v;  // exclusive within block
  if (threadIdx.x == 255) bsum[blockIdx.x] = tmp[255];
}

// ---------- scan2: exclusive scan of up to 2048 block sums (2/thread) ----------
__global__ void scan2_kernel(int* bsum, int nb) {
  __shared__ int tmp[1024];
  const int t = threadIdx.x;  // 1024
  int v0 = (2 * t < nb) ? bsum[2 * t] : 0;
  int v1 = (2 * t + 1 < nb) ? bsum[2 * t + 1] : 0;
  int s = v0 + v1;
  tmp[t] = s;
  __syncthreads();
  for (int off = 1; off < 1024; off <<= 1) {
    int t2 = (t >= off) ? tmp[t - off] : 0;
    __syncthreads();
    tmp[t] += t2;
    __syncthreads();
  }
  int excl = tmp[t] - s;
  if (2 * t < nb) bsum[2 * t] = excl;
  if (2 * t + 1 < nb) bsum[2 * t + 1] = excl + v0;
}

// ---------- scatter: pairs into bucket partitions; XCD-affine slots ----------
__global__ __launch_bounds__(256) void scatter_kernel(const void* ei, const int* hist,
                                                      const int* bsum,
                                                      unsigned int* pairs) {
  __shared__ int cd[NBKT], cs[NBKT], sh[1];
  const int is64 = detect64_block((const unsigned int*)ei, sh);
  const int pj = permb(blockIdx.x);
  for (int k = threadIdx.x; k < NBKT; k += 256) {
    cd[k] = hist[k * B1 + pj] + bsum[k];
    cs[k] = hist[HIST_N + k * B1 + pj] + bsum[NBKT + k];
  }
  __syncthreads();
  for (int g = blockIdx.x * 256 + threadIdx.x; g < N_EDGES / 4; g += B1 * 256) {
    int r[4], c[4];
    load4(ei, is64, 0, g * 4, r);
    load4(ei, is64, 1, g * 4, c);
#pragma unroll
    for (int k = 0; k < 4; k++) {
      int pd = atomicAdd(&cd[c[k] >> BKT_SHIFT], 1);
      pairs[pd] = ((unsigned int)(c[k] & (BKT_SIZE - 1)) << 17) | (unsigned int)r[k];
      int ps = atomicAdd(&cs[r[k] >> BKT_SHIFT], 1);
      pairs[ps] = ((unsigned int)(r[k] & (BKT_SIZE - 1)) << 17) | (unsigned int)c[k];
    }
  }
}

// ---------- csrA: per-bucket count + scan -> rowptr + dinv (no scatter) ----------
__global__ __launch_bounds__(256) void csrA_kernel(const int* hist, const int* bsum,
                                                   const unsigned int* pairs,
                                                   int* rowptr, float* dinv) {
  __shared__ int cnt[BKT_SIZE], sc[BKT_SIZE];
  const int k = blockIdx.x;
  const int base = hist[k * B1] + bsum[k];
  const int end = (k == NBKT - 1) ? N_EDGES : hist[(k + 1) * B1] + bsum[k + 1];
  const int nseg = end - base;
  const int l = threadIdx.x;
  if (l < BKT_SIZE) cnt[l] = 0;
  __syncthreads();
  for (int i = l; i < nseg; i += 256) atomicAdd(&cnt[pairs[base + i] >> 17], 1);
  __syncthreads();
  if (l < BKT_SIZE) sc[l] = cnt[l];
  __syncthreads();
  for (int off = 1; off < BKT_SIZE; off <<= 1) {
    int v = (l < BKT_SIZE && l >= off) ? sc[l - off] : 0;
    __syncthreads();
    if (l < BKT_SIZE) sc[l] += v;
    __syncthreads();
  }
  if (l < BKT_SIZE) {
    int excl = sc[l] - cnt[l];
    int v = k * BKT_SIZE + l;
    if (v < N_NODES) {
      rowptr[v] = base + excl;
      dinv[v] = rsqrtf((float)(cnt[l] + 1));
    }
  }
  if (k == NBKT - 1 && l == 0) rowptr[N_NODES] = N_EDGES;
}

// ---------- csrB + outsum fused (role by blockIdx) ----------
__global__ __launch_bounds__(256) void csrBout_kernel(const int* hist, const int* bsum,
                                                      const unsigned int* pairs,
                                                      const int* __restrict__ rowptr,
                                                      const float* __restrict__ dinv,
                                                      unsigned int* __restrict__ csr,
                                                      float* __restrict__ wacc) {
  if (blockIdx.x < NBKT) {
    // ---- csrB role: scatter with bf16(dinv[src]) packed ----
    __shared__ int cur[BKT_SIZE];
    const int k = blockIdx.x;
    const int base = hist[k * B1] + bsum[k];
    const int end = (k == NBKT - 1) ? N_EDGES : hist[(k + 1) * B1] + bsum[k + 1];
    const int nseg = end - base;
    const int l = threadIdx.x;
    if (l < BKT_SIZE) {
      int v = k * BKT_SIZE + l;
      cur[l] = (v < N_NODES) ? rowptr[v] : 0;
    }
    __syncthreads();
    for (int i = l; i < nseg; i += 256) {
      unsigned int pk = pairs[base + i];
      unsigned int src = pk & 0x1FFFFu;
      int pos = atomicAdd(&cur[pk >> 17], 1);
      unsigned int bits = f2bf(dinv[src]);  // 400KB table, L2-hot here
      csr[pos] = (bits << 17) | src;
    }
    return;
  }
  // ---- outsum role ----
  __shared__ float fb[BKT_SIZE];
  const int k = blockIdx.x - NBKT;
  const int base = hist[HIST_N + k * B1] + bsum[NBKT + k];
  const int end =
      (k == NBKT - 1) ? 2 * N_EDGES : hist[HIST_N + (k + 1) * B1] + bsum[NBKT + k + 1];
  if (threadIdx.x < BKT_SIZE) fb[threadIdx.x] = 0.f;
  __syncthreads();
  for (int i = base + threadIdx.x; i < end; i += 256) {
    unsigned int pk = pairs[i];
    atomicAdd(&fb[pk >> 17], dinv[pk & 0x1FFFFu]);
  }
  __syncthreads();
  int v = k * BKT_SIZE + threadIdx.x;
  if (threadIdx.x < BKT_SIZE && v < N_NODES) wacc[v] = fb[threadIdx.x];
}

// ---------- aggregate v4: XCD-pinned column-quarter slicing ----------
// G is [4][N_NODES][32] fp8 (quarter-major). Block handles quarter q =
// (blockIdx&7)>>1, so with round-robin block->XCD dispatch each XCD pair's
// 4MB L2 caches one 3.2MB slice: gathers become XCD-local L2 hits (~250cy)
// instead of L3 hops (~700cy), and beyond-L2 traffic drops 152MB -> ~55MB.
// Lane map: cl=lane&7 (dword = 4 cols), slot=lane>>3 (8 edge slots/step).
// Gathers batch-issued 4-at-a-time over a 32-edge unrolled window.
__global__ __launch_bounds__(256) void aggregate_kernel(
    const unsigned int* __restrict__ G, const int* __restrict__ rowptr,
    const unsigned int* __restrict__ csr, const float* __restrict__ dinv,
    const float* __restrict__ wacc, const float* __restrict__ b1,
    float* __restrict__ S) {
  __shared__ float lb[HID_DIM];
  __shared__ float ls[HID_DIM];
  if (threadIdx.x < HID_DIM) {
    lb[threadIdx.x] = b1[threadIdx.x];
    ls[threadIdx.x] = 0.f;
  }
  __syncthreads();

  const int lane = threadIdx.x & 63;
  const int cl = lane & 7;     // dword within quarter: cols 4*cl..4*cl+4
  const int slot = lane >> 3;  // edge slot 0..7
  const int b = blockIdx.x;
  const int q = (b & 7) >> 1;  // quarter (XCD-pinned via round-robin dispatch)
  const int wq = ((b >> 3) << 3) + ((b & 1) << 2) + (threadIdx.x >> 6);  // 0..2047
  const int c0 = wq * NPW;
  const unsigned int* __restrict__ Gq = G + (size_t)q * N_NODES * 8;

  // strip metadata: rowptr[c0..c0+NPW] in lanes 0..NPW, dinv/wacc in 0..NPW-1
  int rp = 0;
  float dvv = 0.f, wvv = 0.f;
  {
    const int ci = c0 + lane;
    if (lane <= NPW && ci <= N_NODES) rp = rowptr[ci];
    if (lane < NPW && ci < N_NODES) { dvv = dinv[ci]; wvv = wacc[ci]; }
  }

  v2f sLo = {0.f, 0.f}, sHi = {0.f, 0.f};
  const int nn = (c0 < N_NODES) ? min(NPW, N_NODES - c0) : 0;

  // prefetch first node's window + self row
  int sNxt = __shfl(rp, 0), eNxt = __shfl(rp, 1);
  unsigned int pwNxt = 0, gSNxt = 0;
  if (nn > 0) {
    if (lane < eNxt - sNxt) pwNxt = __builtin_nontemporal_load(&csr[sNxt + lane]);
    if (slot == 0) gSNxt = Gq[(unsigned)c0 * 8 + cl];
  }

  for (int k = 0; k < nn; ++k) {
    const int s0 = sNxt;
    const int cnum = eNxt - sNxt;
    unsigned int pw = pwNxt;
    const unsigned int gS = gSNxt;
    const float d = __shfl(dvv, k), wa = __shfl(wvv, k);
    if (k + 1 < nn) {  // prefetch next node's window + self row
      sNxt = __shfl(rp, k + 1);
      eNxt = __shfl(rp, k + 2);
      pwNxt = 0;
      if (lane < eNxt - sNxt) pwNxt = __builtin_nontemporal_load(&csr[sNxt + lane]);
      if (slot == 0) gSNxt = Gq[(unsigned)(c0 + k + 1) * 8 + cl];
    }

    v2f aLo = {0.f, 0.f}, aHi = {0.f, 0.f};
    if (slot == 0) {  // self loop, weight d
      aLo = cvt8<false>(gS) * d;
      aHi = cvt8<true>(gS) * d;
    }

    int j0 = 0;
    int wlen = min(64, cnum);
    for (;;) {
      {  // edges [0,32) of window: 4 batch-issued gathers
        unsigned int gb[4];
        float wb[4];
#pragma unroll
        for (int t = 0; t < 4; ++t) {
          const int e = 8 * t + slot;
          const unsigned int p = __shfl(pw, e);
          const bool v = e < wlen;
          wb[t] = v ? wdec(p) : 0.f;
          gb[t] = 0u;
          if (v) gb[t] = Gq[(unsigned)(p & 0x1FFFFu) * 8 + cl];
        }
#pragma unroll
        for (int t = 0; t < 4; ++t) {
          aLo += cvt8<false>(gb[t]) * wb[t];
          aHi += cvt8<true>(gb[t]) * wb[t];
        }
      }
      if (wlen > 32) {  // rare: deg > 32
        unsigned int gb[4];
        float wb[4];
#pragma unroll
        for (int t = 0; t < 4; ++t) {
          const int e = 32 + 8 * t + slot;
          const unsigned int p = __shfl(pw, e);
          const bool v = e < wlen;
          wb[t] = v ? wdec(p) : 0.f;
          gb[t] = 0u;
          if (v) gb[t] = Gq[(unsigned)(p & 0x1FFFFu) * 8 + cl];
        }
#pragma unroll
        for (int t = 0; t < 4; ++t) {
          aLo += cvt8<false>(gb[t]) * wb[t];
          aHi += cvt8<true>(gb[t]) * wb[t];
        }
      }
      j0 += 64;
      if (j0 >= cnum) break;  // essentially always
      wlen = min(64, cnum - j0);
      pw = 0;
      if (lane < wlen) pw = __builtin_nontemporal_load(&csr[s0 + j0 + lane]);
    }

    // reduce across 8 slots (lane bits 3,4,5)
#define RED3(v) \
  v += __shfl_xor(v, 8); v += __shfl_xor(v, 16); v += __shfl_xor(v, 32);
    RED3(aLo.x) RED3(aLo.y) RED3(aHi.x) RED3(aHi.y)
#undef RED3

    if (slot == 0) {
      const float wc = d * (wa + d);  // layer-2 weight
      const float* bb = &lb[q * 32 + 4 * cl];
      sLo.x += wc * fmaxf(fmaf(d, aLo.x, bb[0]), 0.f);
      sLo.y += wc * fmaxf(fmaf(d, aLo.y, bb[1]), 0.f);
      sHi.x += wc * fmaxf(fmaf(d, aHi.x, bb[2]), 0.f);
      sHi.y += wc * fmaxf(fmaf(d, aHi.y, bb[3]), 0.f);
    }
  }

  if (slot == 0) {
    atomicAdd(&ls[q * 32 + 4 * cl + 0], sLo.x);
    atomicAdd(&ls[q * 32 + 4 * cl + 1], sLo.y);
    atomicAdd(&ls[q * 32 + 4 * cl + 2], sHi.x);
    atomicAdd(&ls[q * 32 + 4 * cl + 3], sHi.y);
  }
  __syncthreads();
  if (threadIdx.x < 32) {
    const int col = q * 32 + threadIdx.x;
    atomicAdd(&S[col], ls[col]);
  }
}

// ---------- out[j] = (1/N) * S @ W2 + b2 ----------
__global__ void finish_kernel(const float* __restrict__ S, const float* __restrict__ W2,
                              const float* __restrict__ b2, float* __restrict__ out) {
  int j = threadIdx.x;  // 64
  float acc = 0.f;
  for (int k = 0; k < HID_DIM; k++) acc += S[k] * W2[k * OUT_DIM + j];
  out[j] = acc * (1.0f / N_NODES) + b2[j];
}

extern "C" void kernel_launch(void* const* d_in, const int* in_sizes, int n_in,
                              void* d_out, int out_size, void* d_ws, size_t ws_size,
                              hipStream_t stream) {
  const float* x  = (const float*)d_in[0];
  const void*  ei = d_in[1];
  const float* W1 = (const float*)d_in[2];
  const float* b1 = (const float*)d_in[3];
  const float* W2 = (const float*)d_in[4];
  const float* b2 = (const float*)d_in[5];
  float* out = (float*)d_out;

  char* p = (char*)d_ws;
  size_t off = 0;
  auto alloc = [&](size_t bytes) -> void* {
    void* r = p + off;
    off = (off + bytes + 63) & ~(size_t)63;
    return r;
  };
  int*   hist   = (int*)alloc((size_t)HIST_N2 * 4);                // 1.6 MB
  int*   bsum   = (int*)alloc(2048 * 4);
  unsigned int* pairs = (unsigned int*)alloc((size_t)2 * N_EDGES * 4);  // 12.8 MB
  int*   rowptr = (int*)alloc(((size_t)N_NODES + 1) * 4);
  unsigned int* csr = (unsigned int*)alloc((size_t)N_EDGES * 4);   // 6.4 MB
  float* dinv   = (float*)alloc((size_t)N_NODES * 4);
  float* wacc   = (float*)alloc((size_t)N_NODES * 4);
  float* S      = (float*)alloc(HID_DIM * 4);
  unsigned int* G = (unsigned int*)alloc((size_t)N_NODES * HID_DIM);  // 12.8 MB fp8
  (void)ws_size; (void)n_in; (void)in_sizes; (void)out_size;

  const int NBH = HIST_N2 / 256;  // 1564, exact

  front_kernel<<<GEMM_BLKS + B1, 256, 0, stream>>>(x, W1, ei, G, hist, S);
  scan1_kernel<<<NBH, 256, 0, stream>>>(hist, bsum, HIST_N2);
  scan2_kernel<<<1, 1024, 0, stream>>>(bsum, NBH);
  scatter_kernel<<<B1, 256, 0, stream>>>(ei, hist, bsum, pairs);
  csrA_kernel<<<NBKT, 256, 0, stream>>>(hist, bsum, pairs, rowptr, dinv);
  csrBout_kernel<<<2 * NBKT, 256, 0, stream>>>(hist, bsum, pairs, rowptr, dinv, csr,
                                               wacc);
  aggregate_kernel<<<AGG_BLKS, 256, 0, stream>>>(G, rowptr, csr, dinv, wacc, b1, S);
  finish_kernel<<<1, 64, 0, stream>>>(S, W2, b2, out);
}